// Round 1
// baseline (489.416 us; speedup 1.0000x reference)
//
#include <hip/hip_runtime.h>

#define BB 32
#define CC 3
#define HH 512
#define WW 512
#define KS 7
#define PADR 3
#define HW (HH*WW)
#define TS 32
#define TP (TS + KS - 1)  // 38

__global__ void residual_kernel(const float* __restrict__ net, const float* __restrict__ gt,
                                float* __restrict__ res, double* __restrict__ bsum,
                                double* __restrict__ bsumsq) {
    int idx = blockIdx.x * blockDim.x + threadIdx.x;   // 0 .. B*HW-1
    int b = idx / HW;        // HW % 256 == 0, so b is uniform per block
    int hw = idx - b * HW;
    const float* n0 = net + (size_t)b * CC * HW + hw;
    const float* g0 = gt  + (size_t)b * CC * HW + hw;
    float r = fabsf(g0[0] - n0[0]) + fabsf(g0[HW] - n0[HW]) + fabsf(g0[2*HW] - n0[2*HW]);
    res[idx] = r;

    float s = r, s2 = r * r;
    #pragma unroll
    for (int off = 32; off > 0; off >>= 1) {
        s  += __shfl_down(s,  off);
        s2 += __shfl_down(s2, off);
    }
    __shared__ float ls[4], ls2[4];
    int lane = threadIdx.x & 63, wid = threadIdx.x >> 6;
    if (lane == 0) { ls[wid] = s; ls2[wid] = s2; }
    __syncthreads();
    if (threadIdx.x == 0) {
        float ts  = ls[0]  + ls[1]  + ls[2]  + ls[3];
        float ts2 = ls2[0] + ls2[1] + ls2[2] + ls2[3];
        atomicAdd(&bsum[b],   (double)ts);
        atomicAdd(&bsumsq[b], (double)ts2);
    }
}

__global__ void patchw_kernel(const double* __restrict__ bsum, const double* __restrict__ bsumsq,
                              float* __restrict__ patchw) {
    int b = threadIdx.x;
    if (b < BB) {
        double N = (double)HW;
        double var = (bsumsq[b] - bsum[b] * bsum[b] / N) / (N - 1.0);
        patchw[b] = (float)pow(var, 0.2);
    }
}

__global__ void pixel_kernel(const float* __restrict__ res, const float* __restrict__ patchw,
                             double* __restrict__ total) {
    __shared__ float tile[TP][TP + 2];      // 38 x 40, conflict-free rows
    __shared__ float h1[TP][TS], h2[TP][TS];

    int b  = blockIdx.z;
    int r0 = blockIdx.y * TS, c0 = blockIdx.x * TS;
    const float* rb = res + (size_t)b * HW;
    int tid = threadIdx.y * 32 + threadIdx.x;   // block (32,8) -> 0..255

    // load 38x38 reflect-padded tile
    for (int i = tid; i < TP * TP; i += 256) {
        int rr = i / TP, cc = i - rr * TP;
        int gr = r0 + rr - PADR; if (gr < 0) gr = -gr; if (gr >= HH) gr = 2*HH - 2 - gr;
        int gc = c0 + cc - PADR; if (gc < 0) gc = -gc; if (gc >= WW) gc = 2*WW - 2 - gc;
        tile[rr][cc] = rb[gr * WW + gc];
    }
    __syncthreads();

    // horizontal 7-tap sums: 38 rows x 32 output cols
    for (int i = tid; i < TP * TS; i += 256) {
        int rr = i / TS, cc = i - rr * TS;
        float a = 0.f, aa = 0.f;
        #pragma unroll
        for (int k = 0; k < KS; k++) { float v = tile[rr][cc + k]; a += v; aa += v * v; }
        h1[rr][cc] = a; h2[rr][cc] = aa;
    }
    __syncthreads();

    // vertical 7-tap + accumulate pixel_w * residual
    float acc = 0.f;
    for (int rr = threadIdx.y; rr < TS; rr += 8) {
        int cc = threadIdx.x;
        float s1 = 0.f, s2 = 0.f;
        #pragma unroll
        for (int k = 0; k < KS; k++) { s1 += h1[rr + k][cc]; s2 += h2[rr + k][cc]; }
        float pw = (s2 - s1 * s1 * (1.0f / 49.0f)) * (1.0f / 48.0f);
        acc += pw * tile[rr + PADR][cc + PADR];
    }

    #pragma unroll
    for (int off = 32; off > 0; off >>= 1) acc += __shfl_down(acc, off);
    __shared__ float part[4];
    int lane = tid & 63, wid = tid >> 6;
    if (lane == 0) part[wid] = acc;
    __syncthreads();
    if (tid == 0) {
        float t = part[0] + part[1] + part[2] + part[3];
        atomicAdd(total, (double)(t * patchw[b]));
    }
}

__global__ void final_kernel(const double* __restrict__ total, float* __restrict__ out) {
    out[0] = (float)(total[0] / ((double)BB * CC * HW));
}

extern "C" void kernel_launch(void* const* d_in, const int* in_sizes, int n_in,
                              void* d_out, int out_size, void* d_ws, size_t ws_size,
                              hipStream_t stream) {
    const float* net = (const float*)d_in[0];
    const float* gt  = (const float*)d_in[1];
    float* out = (float*)d_out;

    char* ws = (char*)d_ws;
    size_t res_bytes = (size_t)BB * HW * sizeof(float);          // 32 MB
    float*  res    = (float*)ws;
    double* bsum   = (double*)(ws + res_bytes);                  // 32 doubles
    double* bsumsq = (double*)(ws + res_bytes + 256);            // 32 doubles
    double* total  = (double*)(ws + res_bytes + 512);            // 1 double
    float*  patchw = (float*) (ws + res_bytes + 520);            // 32 floats

    // zero the accumulators (ws is poisoned 0xAA before every launch)
    hipMemsetAsync(ws + res_bytes, 0, 520, stream);

    residual_kernel<<<BB * HW / 256, 256, 0, stream>>>(net, gt, res, bsum, bsumsq);
    patchw_kernel<<<1, 64, 0, stream>>>(bsum, bsumsq, patchw);
    dim3 grid(WW / TS, HH / TS, BB);
    dim3 blk(32, 8);
    pixel_kernel<<<grid, blk, 0, stream>>>(res, patchw, total);
    final_kernel<<<1, 1, 0, stream>>>(total, out);
}

// Round 2
// 240.912 us; speedup vs baseline: 2.0315x; 2.0315x over previous
//
#include <hip/hip_runtime.h>

#define BB 32
#define CC 3
#define HH 512
#define WW 512
#define KS 7
#define PADR 3
#define HW (HH*WW)
#define TS 32
#define TP (TS + KS - 1)   // 38
#define TBX (WW / TS)      // 16 tiles per row
#define NTILE (TBX * TBX)  // 256 tiles per batch
#define NBLK (NTILE * BB)  // 8192 blocks

// One pass: recompute residual in 38x38 reflect halo from net/gt, separable
// 7x7 box sums -> local variance (pixel_w), accumulate per-block partials:
//   {sum r, sum r^2, sum pixel_w * r} over the 32x32 interior.
// Written NON-atomically, one float4 per block (no global atomic contention).
__global__ __launch_bounds__(256) void fused_kernel(const float* __restrict__ net,
                                                    const float* __restrict__ gt,
                                                    float4* __restrict__ partials) {
    __shared__ float tile[TP][TP + 2];     // 38 x 40 rows, conflict-free
    __shared__ float h1[TP][TS], h2[TP][TS];

    int b  = blockIdx.z;
    int r0 = blockIdx.y * TS, c0 = blockIdx.x * TS;
    const float* nb = net + (size_t)b * CC * HW;
    const float* gb = gt  + (size_t)b * CC * HW;
    int tid = threadIdx.y * 32 + threadIdx.x;   // block (32,8) -> 0..255

    // build reflect-padded residual tile directly from inputs
    for (int i = tid; i < TP * TP; i += 256) {
        int rr = i / TP, cc = i - rr * TP;
        int gr = r0 + rr - PADR; gr = (gr < 0) ? -gr : ((gr >= HH) ? 2*HH - 2 - gr : gr);
        int gc = c0 + cc - PADR; gc = (gc < 0) ? -gc : ((gc >= WW) ? 2*WW - 2 - gc : gc);
        int off = gr * WW + gc;
        float r = fabsf(gb[off]        - nb[off])
                + fabsf(gb[HW + off]   - nb[HW + off])
                + fabsf(gb[2*HW + off] - nb[2*HW + off]);
        tile[rr][cc] = r;
    }
    __syncthreads();

    // horizontal 7-tap sums: 38 rows x 32 output cols
    for (int i = tid; i < TP * TS; i += 256) {
        int rr = i / TS, cc = i - rr * TS;
        float a = 0.f, aa = 0.f;
        #pragma unroll
        for (int k = 0; k < KS; k++) { float v = tile[rr][cc + k]; a += v; aa += v * v; }
        h1[rr][cc] = a; h2[rr][cc] = aa;
    }
    __syncthreads();

    // vertical 7-tap + per-thread partials over interior
    float sr = 0.f, sr2 = 0.f, tot = 0.f;
    for (int rr = threadIdx.y; rr < TS; rr += 8) {
        int cc = threadIdx.x;
        float s1 = 0.f, s2 = 0.f;
        #pragma unroll
        for (int k = 0; k < KS; k++) { s1 += h1[rr + k][cc]; s2 += h2[rr + k][cc]; }
        float pw = (s2 - s1 * s1 * (1.0f / 49.0f)) * (1.0f / 48.0f);
        float r  = tile[rr + PADR][cc + PADR];
        sr += r; sr2 += r * r; tot += pw * r;
    }

    // block-reduce the three partials
    #pragma unroll
    for (int off = 32; off > 0; off >>= 1) {
        sr  += __shfl_down(sr,  off);
        sr2 += __shfl_down(sr2, off);
        tot += __shfl_down(tot, off);
    }
    __shared__ float p0[4], p1[4], p2[4];
    int lane = tid & 63, wid = tid >> 6;
    if (lane == 0) { p0[wid] = sr; p1[wid] = sr2; p2[wid] = tot; }
    __syncthreads();
    if (tid == 0) {
        int blkid = (b * TBX + blockIdx.y) * TBX + blockIdx.x;
        partials[blkid] = make_float4(p0[0] + p0[1] + p0[2] + p0[3],
                                      p1[0] + p1[1] + p1[2] + p1[3],
                                      p2[0] + p2[1] + p2[2] + p2[3], 0.f);
    }
}

// One block per batch: fold 256 float4 partials in f64, compute patch_w,
// write patch_w * tot per batch. Deterministic, atomic-free.
__global__ __launch_bounds__(256) void reduce_kernel(const float4* __restrict__ partials,
                                                     double* __restrict__ pb) {
    int b = blockIdx.x;
    float4 v = partials[b * NTILE + threadIdx.x];
    double s1 = v.x, s2 = v.y, t = v.z;
    #pragma unroll
    for (int off = 32; off > 0; off >>= 1) {
        s1 += __shfl_down(s1, off);
        s2 += __shfl_down(s2, off);
        t  += __shfl_down(t,  off);
    }
    __shared__ double q0[4], q1[4], q2[4];
    int lane = threadIdx.x & 63, wid = threadIdx.x >> 6;
    if (lane == 0) { q0[wid] = s1; q1[wid] = s2; q2[wid] = t; }
    __syncthreads();
    if (threadIdx.x == 0) {
        double S1 = q0[0] + q0[1] + q0[2] + q0[3];
        double S2 = q1[0] + q1[1] + q1[2] + q1[3];
        double T  = q2[0] + q2[1] + q2[2] + q2[3];
        double N  = (double)HW;
        double var = (S2 - S1 * S1 / N) / (N - 1.0);
        pb[b] = pow(var, 0.2) * T;
    }
}

__global__ void final_kernel(const double* __restrict__ pb, float* __restrict__ out) {
    double v = (threadIdx.x < BB) ? pb[threadIdx.x] : 0.0;
    #pragma unroll
    for (int off = 32; off > 0; off >>= 1) v += __shfl_down(v, off);
    if (threadIdx.x == 0) out[0] = (float)(v / ((double)BB * CC * HW));
}

extern "C" void kernel_launch(void* const* d_in, const int* in_sizes, int n_in,
                              void* d_out, int out_size, void* d_ws, size_t ws_size,
                              hipStream_t stream) {
    const float* net = (const float*)d_in[0];
    const float* gt  = (const float*)d_in[1];
    float* out = (float*)d_out;

    char* ws = (char*)d_ws;
    float4* partials = (float4*)ws;                          // 8192 * 16B = 128 KB
    double* pb       = (double*)(ws + NBLK * sizeof(float4)); // 32 doubles

    dim3 grid(TBX, TBX, BB);
    dim3 blk(32, 8);
    fused_kernel<<<grid, blk, 0, stream>>>(net, gt, partials);
    reduce_kernel<<<BB, NTILE, 0, stream>>>(partials, pb);
    final_kernel<<<1, 64, 0, stream>>>(pb, out);
}

// Round 3
// 224.126 us; speedup vs baseline: 2.1837x; 1.0749x over previous
//
#include <hip/hip_runtime.h>

#define BB 32
#define CC 3
#define HH 512
#define WW 512
#define HW (HH*WW)
#define BAND 32
#define SW 256              // strip width (columns per block)
#define NBAND (HH/BAND)     // 16
#define NSTRIP (WW/SW)      // 2
#define NBLK (BB*NBAND*NSTRIP)  // 1024

__device__ __forceinline__ int refl(int x, int n) {
    x = (x < 0) ? -x : x;
    return (x >= n) ? (2*n - 2 - x) : x;
}

// Streaming band kernel: each block = 256 cols x 32 rows (+3 halo top/bottom).
// Residual rows staged in a 2-deep LDS ring (needed only for the +/-3 horizontal
// neighborhood); h1/h2/center-residual live in 8-deep per-thread register rings
// with static indexing. One syncthreads per row.
__global__ __launch_bounds__(256) void fused_kernel(const float* __restrict__ net,
                                                    const float* __restrict__ gt,
                                                    float4* __restrict__ partials) {
    const int b = blockIdx.z, band = blockIdx.y, strip = blockIdx.x;
    const int bs = band * BAND, be = bs + BAND;   // bs % 8 == 0 (static ring indices rely on this)
    const int c0 = strip * SW;
    const int tid = threadIdx.x;

    __shared__ float resbuf[2][SW + 8];

    const float* nb = net + (size_t)b * CC * HW;
    const float* gb = gt  + (size_t)b * CC * HW;

    const int gc0 = refl(c0 - 3 + tid, WW);       // staging column (reflected)
    const bool halo = tid < 6;
    const int gc1 = halo ? refl(c0 - 3 + SW + tid, WW) : 0;

    float hr1[8], hr2[8], rr[8];
    float sr = 0.f, sr2 = 0.f, tot = 0.f;

    // prefetch produced-row bs-3
    int ro = refl(bs - 3, HH) * WW;
    float a0 = nb[ro+gc0], a1 = nb[HW+ro+gc0], a2 = nb[2*HW+ro+gc0];
    float g0 = gb[ro+gc0], g1 = gb[HW+ro+gc0], g2 = gb[2*HW+ro+gc0];
    float A0=0, A1=0, A2=0, G0=0, G1=0, G2=0;
    if (halo) { A0 = nb[ro+gc1]; A1 = nb[HW+ro+gc1]; A2 = nb[2*HW+ro+gc1];
                G0 = gb[ro+gc1]; G1 = gb[HW+ro+gc1]; G2 = gb[2*HW+ro+gc1]; }

    // prologue: produce rows bs-3 .. bs+2  (slot (5+p)&7, buf (p+1)&1)
    #pragma unroll
    for (int p = 0; p < 6; ++p) {
        const int prow = bs - 3 + p;
        const int slot = (5 + p) & 7;
        const int buf  = (p + 1) & 1;
        float r0v = fabsf(g0-a0) + fabsf(g1-a1) + fabsf(g2-a2);
        float r1v = 0.f;
        if (halo) r1v = fabsf(G0-A0) + fabsf(G1-A1) + fabsf(G2-A2);
        // prefetch next produced row
        ro = refl(prow + 1, HH) * WW;
        a0 = nb[ro+gc0]; a1 = nb[HW+ro+gc0]; a2 = nb[2*HW+ro+gc0];
        g0 = gb[ro+gc0]; g1 = gb[HW+ro+gc0]; g2 = gb[2*HW+ro+gc0];
        if (halo) { A0 = nb[ro+gc1]; A1 = nb[HW+ro+gc1]; A2 = nb[2*HW+ro+gc1];
                    G0 = gb[ro+gc1]; G1 = gb[HW+ro+gc1]; G2 = gb[2*HW+ro+gc1]; }
        resbuf[buf][tid] = r0v;
        if (halo) resbuf[buf][SW + tid] = r1v;
        __syncthreads();
        float s1 = 0.f, s2 = 0.f, own = 0.f;
        #pragma unroll
        for (int k = 0; k < 7; ++k) {
            float v = resbuf[buf][tid + k];
            s1 += v; s2 += v * v;
            if (k == 3) own = v;
        }
        hr1[slot] = s1; hr2[slot] = s2; rr[slot] = own;
        if (p >= 3) { sr += own; sr2 += own * own; }   // rows bs..bs+2
    }

    // main loop: output rows r = bs..be-1; produce row r+3 (slot (j+3)&7, buf (j+1)&1)
    for (int r0 = bs; r0 < be; r0 += 8) {
        #pragma unroll
        for (int j = 0; j < 8; ++j) {
            const int r = r0 + j;
            const int prow = r + 3;
            const int slot = (j + 3) & 7;
            const int buf  = (j + 1) & 1;
            float r0v = fabsf(g0-a0) + fabsf(g1-a1) + fabsf(g2-a2);
            float r1v = 0.f;
            if (halo) r1v = fabsf(G0-A0) + fabsf(G1-A1) + fabsf(G2-A2);
            // prefetch next produced row (reflect keeps it in-bounds; last is wasted)
            ro = refl(prow + 1, HH) * WW;
            a0 = nb[ro+gc0]; a1 = nb[HW+ro+gc0]; a2 = nb[2*HW+ro+gc0];
            g0 = gb[ro+gc0]; g1 = gb[HW+ro+gc0]; g2 = gb[2*HW+ro+gc0];
            if (halo) { A0 = nb[ro+gc1]; A1 = nb[HW+ro+gc1]; A2 = nb[2*HW+ro+gc1];
                        G0 = gb[ro+gc1]; G1 = gb[HW+ro+gc1]; G2 = gb[2*HW+ro+gc1]; }
            resbuf[buf][tid] = r0v;
            if (halo) resbuf[buf][SW + tid] = r1v;
            __syncthreads();
            // horizontal 7-tap for produced row (own column)
            float s1 = 0.f, s2 = 0.f, own = 0.f;
            #pragma unroll
            for (int k = 0; k < 7; ++k) {
                float v = resbuf[buf][tid + k];
                s1 += v; s2 += v * v;
                if (k == 3) own = v;
            }
            hr1[slot] = s1; hr2[slot] = s2; rr[slot] = own;
            if (prow < be) { sr += own; sr2 += own * own; }
            // vertical 7-tap for output row r: slots (r-3+k)&7 = (j+5+k)&7
            float v1 = 0.f, v2 = 0.f;
            #pragma unroll
            for (int k = 0; k < 7; ++k) {
                v1 += hr1[(j + 5 + k) & 7];
                v2 += hr2[(j + 5 + k) & 7];
            }
            float pw = (v2 - v1 * v1 * (1.0f/49.0f)) * (1.0f/48.0f);
            tot += pw * rr[j & 7];
        }
    }

    // block reduction of the three partials
    #pragma unroll
    for (int off = 32; off > 0; off >>= 1) {
        sr  += __shfl_down(sr,  off);
        sr2 += __shfl_down(sr2, off);
        tot += __shfl_down(tot, off);
    }
    __shared__ float red[3][4];
    const int lane = tid & 63, wid = tid >> 6;
    if (lane == 0) { red[0][wid] = sr; red[1][wid] = sr2; red[2][wid] = tot; }
    __syncthreads();
    if (tid == 0) {
        const int blkid = (b * NBAND + band) * NSTRIP + strip;
        partials[blkid] = make_float4(red[0][0]+red[0][1]+red[0][2]+red[0][3],
                                      red[1][0]+red[1][1]+red[1][2]+red[1][3],
                                      red[2][0]+red[2][1]+red[2][2]+red[2][3], 0.f);
    }
}

// Single block: fold 32 partials per batch (f64), patch_w = var^0.2, sum over batches.
__global__ __launch_bounds__(1024) void finalize_kernel(const float4* __restrict__ partials,
                                                        float* __restrict__ out) {
    const int t = threadIdx.x;          // 0..1023 ; batch = t>>5
    float4 v = partials[t];
    double s1 = v.x, s2 = v.y, tt = v.z;
    #pragma unroll
    for (int off = 16; off > 0; off >>= 1) {
        s1 += __shfl_down(s1, off, 32);
        s2 += __shfl_down(s2, off, 32);
        tt += __shfl_down(tt, off, 32);
    }
    __shared__ double L[3][32];
    if ((t & 31) == 0) { int bb = t >> 5; L[0][bb] = s1; L[1][bb] = s2; L[2][bb] = tt; }
    __syncthreads();
    if (t < 32) {
        double S1 = L[0][t], S2 = L[1][t], T = L[2][t];
        double N = (double)HW;
        double val = pow((S2 - S1 * S1 / N) / (N - 1.0), 0.2) * T;
        #pragma unroll
        for (int off = 16; off > 0; off >>= 1) val += __shfl_down(val, off, 32);
        if (t == 0) out[0] = (float)(val / ((double)BB * CC * HW));
    }
}

extern "C" void kernel_launch(void* const* d_in, const int* in_sizes, int n_in,
                              void* d_out, int out_size, void* d_ws, size_t ws_size,
                              hipStream_t stream) {
    const float* net = (const float*)d_in[0];
    const float* gt  = (const float*)d_in[1];
    float* out = (float*)d_out;

    float4* partials = (float4*)d_ws;   // 1024 * 16B = 16 KB

    dim3 grid(NSTRIP, NBAND, BB);
    fused_kernel<<<grid, 256, 0, stream>>>(net, gt, partials);
    finalize_kernel<<<1, 1024, 0, stream>>>(partials, out);
}